// Round 2
// baseline (1759.205 us; speedup 1.0000x reference)
//
#include <hip/hip_runtime.h>
#include <cstddef>

#define NPTS 500000
#define DF 64
#define NC 10000
#define BN_EPS 1e-5f

#define TPB 256
#define PTILE 64
#define NTILES ((NPTS + PTILE - 1) / PTILE)  // 7813
#define NBLK 1024                            // 4 blocks/CU x 256 CU

// ---- order-preserving float<->uint encoding (for atomic max on floats) ----
__device__ __forceinline__ unsigned f2o(float f) {
  unsigned u = __float_as_uint(f);
  return (u & 0x80000000u) ? ~u : (u | 0x80000000u);
}
__device__ __forceinline__ float o2f(unsigned u) {
  return __uint_as_float((u & 0x80000000u) ? (u ^ 0x80000000u) : ~u);
}

// async global->LDS, 16B per lane. LDS dest is wave-uniform base + lane*16.
__device__ __forceinline__ void gload16(const float* g, float* l) {
  __builtin_amdgcn_global_load_lds(
      (const __attribute__((address_space(1))) void*)g,
      (__attribute__((address_space(3))) void*)l, 16, 0, 0);
}

// Stage one 64-point x tile (16 KB) into a linear LDS buffer.
// PRE-SWIZZLED source: LDS 16B-slot (p, jb) receives x[p][(jb ^ (p&7))*4..],
// so the compute-side read of row p at chunk jb^(p&7) spreads the 64 lanes
// (64 distinct rows, same column) across all 8 bank groups — the rule-21
// "swizzle source + swizzle read, keep dest linear" pattern.
__device__ __forceinline__ void stage_tile(float* xsbuf, const float* x,
                                           int pbase, int wave, int lane) {
#pragma unroll
  for (int i = 0; i < 4; ++i) {
    const int chunk = wave * 4 + i;       // 0..15, wave-uniform
    const int slot = chunk * 64 + lane;   // 16B slot id 0..1023
    const int p = slot >> 4;              // local point 0..63
    const int jb = slot & 15;             // 16B column block
    int gp = pbase + p;
    if (gp >= NPTS) gp = NPTS - 1;        // tail/overshoot: safe garbage row
    const int jsrc = jb ^ (p & 7);
    gload16(x + (size_t)gp * DF + jsrc * 4, xsbuf + chunk * 256);
  }
}

// ws layout (float/uint units):
// 0        : q_u     [NC*DF]   sortable-uint segment max of Q projections
// 640000   : mmax_u  [NC]      sortable-uint segment max of M
// 650000   : denom   [NC]      segment sum of exp
// 660000   : sums    [2*DF]    [sum h | sum h^2]
// 660128   : scale   [DF]
// 660192   : shift   [DF]
// 660256   : Mv      [NPTS]

// Work decomposition: wave w owns features [16w,16w+16); lane = one point of
// the 64-pt tile. W[f][j] is wave-uniform -> scalar (SMEM) loads feed the FMA
// as SGPR operands: zero LDS traffic for W. x: 16 ds_read_b128/thread/tile.
// MODE 0: Q proj -> segment max into q_u (read-filtered atomics)
// MODE 1: K proj -> M = dot(q[c],k) (cross-wave LDS reduce), atomicMax mmax_u
// MODE 2: V proj -> h = attn*v, accumulate BN stats (no h store)
// MODE 3: V proj -> h, normalize + relu, transpose via LDS, coalesced store
template <int MODE>
__launch_bounds__(TPB, 4)
__global__ void proj_kernel(
    const float* __restrict__ x, const int* __restrict__ cluster,
    const float* __restrict__ W, const float* __restrict__ bias,
    unsigned* __restrict__ q_u, unsigned* __restrict__ mmax_u,
    const float* __restrict__ denom, float* __restrict__ Mv,
    float* __restrict__ sums, const float* __restrict__ scale,
    const float* __restrict__ shift, float* __restrict__ out) {
  __shared__ float xs[2][PTILE * DF];  // double-buffered x tiles, 2 x 16 KB
  __shared__ float mred[TPB];          // mode-1 cross-wave dot reduce

  const int tid = threadIdx.x;
  const int lane = tid & 63;
  const int wave = tid >> 6;
  const int uw = __builtin_amdgcn_readfirstlane(wave);  // uniform wave id
  const int f0 = uw * 16;                               // this wave's features
  const float* __restrict__ Wrow = W + (size_t)f0 * DF; // uniform pointer
  const int psw = lane & 7;                             // read-side swizzle

  float s1[16], s2[16];
  if (MODE == 2) {
#pragma unroll
    for (int e = 0; e < 16; ++e) { s1[e] = 0.f; s2[e] = 0.f; }
  }

  // ---- prologue: stage tile t0 into buf0, drain, barrier ----
  int t = blockIdx.x;
  stage_tile(xs[0], x, t * PTILE, wave, lane);
  asm volatile("s_waitcnt vmcnt(0) lgkmcnt(0)" ::: "memory");
  __builtin_amdgcn_s_barrier();
  asm volatile("" ::: "memory");

  int cur = 0;
  for (; t < NTILES; t += NBLK) {
    const int pbase = t * PTILE;
    // prefetch next tile (in flight under the whole GEMM)
    stage_tile(xs[cur ^ 1], x, (t + NBLK) * PTILE, wave, lane);
    const int p = pbase + lane;
    const bool valid = p < NPTS;
    const int cc = cluster[valid ? p : NPTS - 1];
    asm volatile("" ::: "memory");

    // ---- GEMM: acc[f] = x[p] . W[f0+f] + b, W from scalar regs ----
    float acc[16];
#pragma unroll
    for (int e = 0; e < 16; ++e) acc[e] = bias[f0 + e];  // uniform -> s_load
    const float* xrow = &xs[cur][lane * DF];
#pragma unroll
    for (int jb4 = 0; jb4 < 4; ++jb4) {
      float4 xv[4];
#pragma unroll
      for (int i = 0; i < 4; ++i)
        xv[i] = *(const float4*)(xrow + (((jb4 * 4 + i) ^ psw) << 2));
#pragma unroll
      for (int f = 0; f < 16; ++f) {
        const float* wr = Wrow + f * DF + jb4 * 16;  // uniform -> s_load_x16
#pragma unroll
        for (int i = 0; i < 4; ++i) {
          acc[f] = fmaf(xv[i].x, wr[i * 4 + 0], acc[f]);
          acc[f] = fmaf(xv[i].y, wr[i * 4 + 1], acc[f]);
          acc[f] = fmaf(xv[i].z, wr[i * 4 + 2], acc[f]);
          acc[f] = fmaf(xv[i].w, wr[i * 4 + 3], acc[f]);
        }
      }
    }

    // ---- mode-specific epilogue (lane owns point p, features f0..f0+15) ----
    if (MODE == 0) {
      if (valid) {
        unsigned* dst = q_u + (size_t)cc * DF + f0;
#pragma unroll
        for (int i = 0; i < 4; ++i) {
          // monotone q_u: stale read can only under-report -> filter is safe
          const uint4 curq = *(const uint4*)(dst + i * 4);
          const unsigned e0 = f2o(acc[i * 4 + 0]);
          const unsigned e1 = f2o(acc[i * 4 + 1]);
          const unsigned e2 = f2o(acc[i * 4 + 2]);
          const unsigned e3 = f2o(acc[i * 4 + 3]);
          if (e0 > curq.x) atomicMax(dst + i * 4 + 0, e0);
          if (e1 > curq.y) atomicMax(dst + i * 4 + 1, e1);
          if (e2 > curq.z) atomicMax(dst + i * 4 + 2, e2);
          if (e3 > curq.w) atomicMax(dst + i * 4 + 3, e3);
        }
      }
    } else if (MODE == 1) {
      float partial = 0.f;
      if (valid) {
        const unsigned* qp = q_u + (size_t)cc * DF + f0;
#pragma unroll
        for (int i = 0; i < 4; ++i) {
          const uint4 qu = *(const uint4*)(qp + i * 4);
          partial += o2f(qu.x) * acc[i * 4 + 0] + o2f(qu.y) * acc[i * 4 + 1] +
                     o2f(qu.z) * acc[i * 4 + 2] + o2f(qu.w) * acc[i * 4 + 3];
        }
      }
      mred[wave * 64 + lane] = partial;
      asm volatile("s_waitcnt lgkmcnt(0)" ::: "memory");
      __builtin_amdgcn_s_barrier();
      asm volatile("" ::: "memory");
      if (wave == 0 && valid) {
        const float M =
            mred[lane] + mred[64 + lane] + mred[128 + lane] + mred[192 + lane];
        Mv[p] = M;
        const unsigned e = f2o(M);
        unsigned* mm = mmax_u + cc;
        if (e > *mm) atomicMax(mm, e);
      }
    } else if (MODE == 2) {
      if (valid) {
        const float attn = __expf(Mv[p] - o2f(mmax_u[cc])) / denom[cc];
#pragma unroll
        for (int e = 0; e < 16; ++e) {
          const float h = attn * acc[e];
          s1[e] += h;
          s2[e] += h * h;
        }
      }
    } else {  // MODE 3
      float attn = 0.f;
      if (valid) attn = __expf(Mv[p] - o2f(mmax_u[cc])) / denom[cc];
      float r[16];
#pragma unroll
      for (int e = 0; e < 16; ++e)
        r[e] = fmaxf(fmaf(attn * acc[e], scale[f0 + e], shift[f0 + e]), 0.f);
      // barrier A: all waves finished reading xs[cur] -> reuse it as ostage
      asm volatile("" ::: "memory");
      __builtin_amdgcn_s_barrier();
      asm volatile("" ::: "memory");
      float* ost = &xs[cur][0];
#pragma unroll
      for (int i = 0; i < 4; ++i) {
        const int jb = (f0 >> 2) + i;  // feature chunk f0+4i..f0+4i+3
        *(float4*)(ost + lane * DF + ((jb ^ psw) << 2)) =
            make_float4(r[i * 4 + 0], r[i * 4 + 1], r[i * 4 + 2],
                        r[i * 4 + 3]);
      }
      asm volatile("s_waitcnt lgkmcnt(0)" ::: "memory");
      __builtin_amdgcn_s_barrier();  // barrier B: transpose visible
      asm volatile("" ::: "memory");
#pragma unroll
      for (int i = 0; i < 4; ++i) {
        const int g = i * TPB + tid;
        const int pp = g >> 4;
        const int jb = g & 15;
        const int gp = pbase + pp;
        if (gp < NPTS) {
          const float4 v =
              *(const float4*)(&xs[cur][pp * DF + ((jb ^ (pp & 7)) << 2)]);
          *(float4*)(out + (size_t)gp * DF + jb * 4) = v;
        }
      }
    }

    // ---- pipeline turn: drain prefetch (landed during GEMM), one barrier
    asm volatile("s_waitcnt vmcnt(0)" ::: "memory");
    __builtin_amdgcn_s_barrier();
    asm volatile("" ::: "memory");
    cur ^= 1;
  }

  if constexpr (MODE == 2) {
    // per-feature block reduce across the 64 lanes (points), then one atomic
#pragma unroll
    for (int e = 0; e < 16; ++e) {
      float a = s1[e], b = s2[e];
#pragma unroll
      for (int m = 1; m < 64; m <<= 1) {
        a += __shfl_xor(a, m, 64);
        b += __shfl_xor(b, m, 64);
      }
      if (lane == 0) {
        atomicAdd(sums + f0 + e, a);
        atomicAdd(sums + DF + f0 + e, b);
      }
    }
  }
}

__global__ void denom_kernel(const float* __restrict__ Mv,
                             const int* __restrict__ cluster,
                             const unsigned* __restrict__ mmax_u,
                             float* __restrict__ denom) {
  int i = blockIdx.x * blockDim.x + threadIdx.x;
  if (i < NPTS) {
    int c = cluster[i];
    atomicAdd(denom + c, __expf(Mv[i] - o2f(mmax_u[c])));
  }
}

__global__ void finalize_kernel(const float* __restrict__ sums,
                                const float* __restrict__ gamma,
                                const float* __restrict__ beta,
                                float* __restrict__ scale,
                                float* __restrict__ shift) {
  int d = threadIdx.x;
  float mean = sums[d] * (1.0f / NPTS);
  float var = sums[DF + d] * (1.0f / NPTS) - mean * mean;
  float s = gamma[d] * rsqrtf(var + BN_EPS);
  scale[d] = s;
  shift[d] = fmaf(-mean, s, beta[d]);
}

extern "C" void kernel_launch(void* const* d_in, const int* in_sizes, int n_in,
                              void* d_out, int out_size, void* d_ws,
                              size_t ws_size, hipStream_t stream) {
  const float* x = (const float*)d_in[1];
  const int* cluster = (const int*)d_in[2];
  const float* Wv = (const float*)d_in[3];
  const float* bv = (const float*)d_in[4];
  const float* Wk = (const float*)d_in[5];
  const float* bk = (const float*)d_in[6];
  const float* Wq = (const float*)d_in[7];
  const float* bq = (const float*)d_in[8];
  const float* gamma = (const float*)d_in[9];
  const float* beta = (const float*)d_in[10];
  float* out = (float*)d_out;

  float* ws = (float*)d_ws;
  unsigned* q_u = (unsigned*)ws;
  unsigned* mmax_u = (unsigned*)(ws + 640000);
  float* denom = ws + 650000;
  float* sums = ws + 660000;
  float* scale = ws + 660128;
  float* shift = ws + 660192;
  float* Mv = ws + 660256;

  // zero q_u / mmax_u / denom / sums (0u == sortable "-inf" sentinel)
  hipMemsetAsync(d_ws, 0, 660256 * sizeof(float), stream);

  proj_kernel<0><<<NBLK, TPB, 0, stream>>>(x, cluster, Wq, bq, q_u, mmax_u,
                                           denom, Mv, sums, scale, shift, out);
  proj_kernel<1><<<NBLK, TPB, 0, stream>>>(x, cluster, Wk, bk, q_u, mmax_u,
                                           denom, Mv, sums, scale, shift, out);
  denom_kernel<<<(NPTS + 255) / 256, 256, 0, stream>>>(Mv, cluster, mmax_u,
                                                       denom);
  proj_kernel<2><<<NBLK, TPB, 0, stream>>>(x, cluster, Wv, bv, q_u, mmax_u,
                                           denom, Mv, sums, scale, shift, out);
  finalize_kernel<<<1, 64, 0, stream>>>(sums, gamma, beta, scale, shift);
  proj_kernel<3><<<NBLK, TPB, 0, stream>>>(x, cluster, Wv, bv, q_u, mmax_u,
                                           denom, Mv, sums, scale, shift, out);
}

// Round 3
// 568.999 us; speedup vs baseline: 3.0918x; 3.0918x over previous
//
#include <hip/hip_runtime.h>
#include <cstddef>

#define NPTS 500000
#define DF 64
#define NC 10000
#define BN_EPS 1e-5f

#define TPB 256
#define PTILE 64
#define NTILES ((NPTS + PTILE - 1) / PTILE)  // 7813
#define QKBLK 768                            // 3 blocks/CU (49 KB LDS)
#define VBLK 768                             // 3 blocks/CU (49 KB LDS)

// ---- order-preserving float<->uint encoding (for atomic max on floats) ----
__device__ __forceinline__ unsigned f2o(float f) {
  unsigned u = __float_as_uint(f);
  return (u & 0x80000000u) ? ~u : (u | 0x80000000u);
}
__device__ __forceinline__ float o2f(unsigned u) {
  return __uint_as_float((u & 0x80000000u) ? (u ^ 0x80000000u) : ~u);
}

// async global->LDS, 16B per lane. LDS dest is wave-uniform base + lane*16.
__device__ __forceinline__ void gload16(const float* g, float* l) {
  __builtin_amdgcn_global_load_lds(
      (const __attribute__((address_space(1))) void*)g,
      (__attribute__((address_space(3))) void*)l, 16, 0, 0);
}

// Stage one 64-point x tile (16 KB) into a linear LDS buffer via
// global_load_lds_dwordx4. PRE-SWIZZLED source: LDS 16B-slot (p, jb) receives
// x[p][(jb ^ (p>>2))*4 ..]; compute-side reads chunk j4 of row p at slot
// j4 ^ (p>>2) -> conflict-free, dest stays linear (rule 21).
__device__ __forceinline__ void stage_tile(float* xsbuf, const float* x,
                                           int pbase, int wave, int lane) {
#pragma unroll
  for (int i = 0; i < 4; ++i) {
    const int chunk = wave * 4 + i;       // 0..15, wave-uniform
    const int slot = chunk * 64 + lane;   // 16B slot id 0..1023
    const int p = slot >> 4;              // local point 0..63
    const int jb = slot & 15;             // 16B column block
    int gp = pbase + p;
    if (gp >= NPTS) gp = NPTS - 1;        // tail: safe garbage row
    const int jsrc = jb ^ (p >> 2);
    gload16(x + (size_t)gp * DF + jsrc * 4, xsbuf + chunk * 256);
  }
}

// ws layout (float/uint units):
// 0        : q_u     [NC*DF]   sortable-uint segment max of Q projections
// 640000   : mmax_u  [NC]      sortable-uint segment max of M
// 650000   : denom   [NC]      segment sum of exp
// 660000   : sums    [2*DF]    [sum h | sum h^2]
// 660128   : scale   [DF]
// 660192   : shift   [DF]
// 660256   : Mv      [NPTS]
// k rows are staged in d_out (dead until the V pass overwrites it with h).

// ---------------------------------------------------------------------------
// Fused Q+K projection: one x staging, two GEMMs.
//   Q -> read-filtered atomicMax into q_u ; K -> store rows to kout (=d_out).
// Thread (fg=tid&15, pg=tid>>4) owns features f0..f0+3 of points pg*4..+3.
// ---------------------------------------------------------------------------
__launch_bounds__(TPB, 3)
__global__ void qk_kernel(const float* __restrict__ x,
                          const int* __restrict__ cluster,
                          const float* __restrict__ Wq,
                          const float* __restrict__ bq,
                          const float* __restrict__ Wk,
                          const float* __restrict__ bk,
                          unsigned* __restrict__ q_u,
                          float* __restrict__ kout) {
  __shared__ float Wt2[DF * 128];  // Wt2[j][f] : Q at f, K at f+64
  __shared__ float xs[PTILE * DF]; // single-buffered x tile (16 KB)

  const int tid = threadIdx.x;
  const int lane = tid & 63;
  const int wave = tid >> 6;
  const int fg = tid & 15;
  const int pg = tid >> 4;
  const int f0 = fg * 4;

  // ---- stage both W's transposed (once per block) ----
  {
    const int f = tid & 63;
    const int jb = (tid >> 6) * 16;
#pragma unroll
    for (int i = 0; i < 4; ++i) {
      float4 a = *(const float4*)(Wq + f * DF + jb + i * 4);
      Wt2[(jb + i * 4 + 0) * 128 + f] = a.x;
      Wt2[(jb + i * 4 + 1) * 128 + f] = a.y;
      Wt2[(jb + i * 4 + 2) * 128 + f] = a.z;
      Wt2[(jb + i * 4 + 3) * 128 + f] = a.w;
      float4 b = *(const float4*)(Wk + f * DF + jb + i * 4);
      Wt2[(jb + i * 4 + 0) * 128 + 64 + f] = b.x;
      Wt2[(jb + i * 4 + 1) * 128 + 64 + f] = b.y;
      Wt2[(jb + i * 4 + 2) * 128 + 64 + f] = b.z;
      Wt2[(jb + i * 4 + 3) * 128 + 64 + f] = b.w;
    }
  }
  const float4 bq4 = *(const float4*)(bq + f0);
  const float4 bk4 = *(const float4*)(bk + f0);

  for (int t = blockIdx.x; t < NTILES; t += QKBLK) {
    const int pbase = t * PTILE;
    __syncthreads();  // previous tile's readers done (also covers Wt2, iter 0)
    stage_tile(xs, x, pbase, wave, lane);
    // cluster ids for this thread's 4 points
    int4 c4;
    {
      const int cb = pbase + pg * 4;
      if (cb + 3 < NPTS) {
        c4 = *(const int4*)(cluster + cb);
      } else {
        c4.x = cluster[cb + 0 < NPTS ? cb + 0 : NPTS - 1];
        c4.y = cluster[cb + 1 < NPTS ? cb + 1 : NPTS - 1];
        c4.z = cluster[cb + 2 < NPTS ? cb + 2 : NPTS - 1];
        c4.w = cluster[cb + 3 < NPTS ? cb + 3 : NPTS - 1];
      }
    }
    asm volatile("s_waitcnt vmcnt(0) lgkmcnt(0)" ::: "memory");
    __syncthreads();

    // ---- dual GEMM ----
    float4 accQ[4], accK[4];
#pragma unroll
    for (int pp = 0; pp < 4; ++pp) { accQ[pp] = bq4; accK[pp] = bk4; }
#pragma unroll 4
    for (int j4 = 0; j4 < 16; ++j4) {
      float4 wq[4], wk[4];
#pragma unroll
      for (int e = 0; e < 4; ++e) {
        wq[e] = *(const float4*)(Wt2 + (j4 * 4 + e) * 128 + f0);
        wk[e] = *(const float4*)(Wt2 + (j4 * 4 + e) * 128 + 64 + f0);
      }
      const int xoff = (j4 ^ pg) * 4;
#pragma unroll
      for (int pp = 0; pp < 4; ++pp) {
        float4 xv = *(const float4*)(xs + (pg * 4 + pp) * DF + xoff);
        accQ[pp].x = fmaf(xv.x, wq[0].x, accQ[pp].x);
        accQ[pp].y = fmaf(xv.x, wq[0].y, accQ[pp].y);
        accQ[pp].z = fmaf(xv.x, wq[0].z, accQ[pp].z);
        accQ[pp].w = fmaf(xv.x, wq[0].w, accQ[pp].w);
        accQ[pp].x = fmaf(xv.y, wq[1].x, accQ[pp].x);
        accQ[pp].y = fmaf(xv.y, wq[1].y, accQ[pp].y);
        accQ[pp].z = fmaf(xv.y, wq[1].z, accQ[pp].z);
        accQ[pp].w = fmaf(xv.y, wq[1].w, accQ[pp].w);
        accQ[pp].x = fmaf(xv.z, wq[2].x, accQ[pp].x);
        accQ[pp].y = fmaf(xv.z, wq[2].y, accQ[pp].y);
        accQ[pp].z = fmaf(xv.z, wq[2].z, accQ[pp].z);
        accQ[pp].w = fmaf(xv.z, wq[2].w, accQ[pp].w);
        accQ[pp].x = fmaf(xv.w, wq[3].x, accQ[pp].x);
        accQ[pp].y = fmaf(xv.w, wq[3].y, accQ[pp].y);
        accQ[pp].z = fmaf(xv.w, wq[3].z, accQ[pp].z);
        accQ[pp].w = fmaf(xv.w, wq[3].w, accQ[pp].w);
        accK[pp].x = fmaf(xv.x, wk[0].x, accK[pp].x);
        accK[pp].y = fmaf(xv.x, wk[0].y, accK[pp].y);
        accK[pp].z = fmaf(xv.x, wk[0].z, accK[pp].z);
        accK[pp].w = fmaf(xv.x, wk[0].w, accK[pp].w);
        accK[pp].x = fmaf(xv.y, wk[1].x, accK[pp].x);
        accK[pp].y = fmaf(xv.y, wk[1].y, accK[pp].y);
        accK[pp].z = fmaf(xv.y, wk[1].z, accK[pp].z);
        accK[pp].w = fmaf(xv.y, wk[1].w, accK[pp].w);
        accK[pp].x = fmaf(xv.z, wk[2].x, accK[pp].x);
        accK[pp].y = fmaf(xv.z, wk[2].y, accK[pp].y);
        accK[pp].z = fmaf(xv.z, wk[2].z, accK[pp].z);
        accK[pp].w = fmaf(xv.z, wk[2].w, accK[pp].w);
        accK[pp].x = fmaf(xv.w, wk[3].x, accK[pp].x);
        accK[pp].y = fmaf(xv.w, wk[3].y, accK[pp].y);
        accK[pp].z = fmaf(xv.w, wk[3].z, accK[pp].z);
        accK[pp].w = fmaf(xv.w, wk[3].w, accK[pp].w);
      }
    }

    // ---- epilogue: Q segment-max + K row store ----
#pragma unroll
    for (int pp = 0; pp < 4; ++pp) {
      const int p = pbase + pg * 4 + pp;
      if (p < NPTS) {
        const int cc = (pp == 0) ? c4.x : (pp == 1) ? c4.y
                       : (pp == 2) ? c4.z : c4.w;
        unsigned* dst = q_u + (size_t)cc * DF + f0;
        // monotone q_u: stale read only under-reports -> filter is race-safe
        const uint4 curq = *(const uint4*)dst;
        const unsigned ex = f2o(accQ[pp].x);
        const unsigned ey = f2o(accQ[pp].y);
        const unsigned ez = f2o(accQ[pp].z);
        const unsigned ew = f2o(accQ[pp].w);
        if (ex > curq.x) atomicMax(dst + 0, ex);
        if (ey > curq.y) atomicMax(dst + 1, ey);
        if (ez > curq.z) atomicMax(dst + 2, ez);
        if (ew > curq.w) atomicMax(dst + 3, ew);
        *(float4*)(kout + (size_t)p * DF + f0) = accK[pp];
      }
    }
  }
}

// ---------------------------------------------------------------------------
// M = dot(q[cluster[p]], k[p]) ; Mv[p] = M ; segment-max into mmax_u.
// Same fg/pg layout: coalesced k rows, q_u row gather covered by 16 fg lanes.
// ---------------------------------------------------------------------------
__global__ void mdot_kernel(const float* __restrict__ k,
                            const int* __restrict__ cluster,
                            const unsigned* __restrict__ q_u,
                            float* __restrict__ Mv,
                            unsigned* __restrict__ mmax_u) {
  const int tid = threadIdx.x;
  const int fg = tid & 15;
  const int pg = tid >> 4;
  const int f0 = fg * 4;
  const int pbase = blockIdx.x * PTILE;
#pragma unroll
  for (int pp = 0; pp < 4; ++pp) {
    const int p = pbase + pg * 4 + pp;
    float partial = 0.f;
    int cc = 0;
    if (p < NPTS) {
      cc = cluster[p];
      const float4 kv = *(const float4*)(k + (size_t)p * DF + f0);
      const uint4 qu = *(const uint4*)(q_u + (size_t)cc * DF + f0);
      partial = o2f(qu.x) * kv.x + o2f(qu.y) * kv.y + o2f(qu.z) * kv.z +
                o2f(qu.w) * kv.w;
    }
    partial += __shfl_xor(partial, 1, 64);
    partial += __shfl_xor(partial, 2, 64);
    partial += __shfl_xor(partial, 4, 64);
    partial += __shfl_xor(partial, 8, 64);
    if (fg == 0 && p < NPTS) {
      Mv[p] = partial;
      const unsigned e = f2o(partial);
      unsigned* mm = mmax_u + cc;
      if (e > *mm) atomicMax(mm, e);
    }
  }
}

__global__ void denom_kernel(const float* __restrict__ Mv,
                             const int* __restrict__ cluster,
                             const unsigned* __restrict__ mmax_u,
                             float* __restrict__ denom) {
  int i = blockIdx.x * blockDim.x + threadIdx.x;
  if (i < NPTS) {
    int c = cluster[i];
    atomicAdd(denom + c, __expf(Mv[i] - o2f(mmax_u[c])));
  }
}

// ---------------------------------------------------------------------------
// V projection: h = attn*v stored to out, BN sums accumulated.
// Round-1 mode-2 structure (double-buffered gload_lds staging) + h store.
// ---------------------------------------------------------------------------
__launch_bounds__(TPB, 3)
__global__ void v_kernel(const float* __restrict__ x,
                         const int* __restrict__ cluster,
                         const float* __restrict__ Wv,
                         const float* __restrict__ bv,
                         const unsigned* __restrict__ mmax_u,
                         const float* __restrict__ denom,
                         const float* __restrict__ Mv,
                         float* __restrict__ sums,
                         float* __restrict__ out) {
  __shared__ float Wt[DF * DF];        // Wt[j][f]
  __shared__ float xs[2][PTILE * DF];  // double-buffered x tiles

  const int tid = threadIdx.x;
  const int lane = tid & 63;
  const int wave = tid >> 6;
  const int fg = tid & 15;
  const int pg = tid >> 4;
  const int f0 = fg * 4;

  {
    const int f = tid & 63;
    const int jb = (tid >> 6) * 16;
#pragma unroll
    for (int i = 0; i < 4; ++i) {
      float4 wr = *(const float4*)(Wv + f * DF + jb + i * 4);
      Wt[(jb + i * 4 + 0) * DF + f] = wr.x;
      Wt[(jb + i * 4 + 1) * DF + f] = wr.y;
      Wt[(jb + i * 4 + 2) * DF + f] = wr.z;
      Wt[(jb + i * 4 + 3) * DF + f] = wr.w;
    }
  }
  const float4 bv4 = *(const float4*)(bv + f0);
  float4 s1 = make_float4(0.f, 0.f, 0.f, 0.f);
  float4 s2 = make_float4(0.f, 0.f, 0.f, 0.f);

  int t = blockIdx.x;
  stage_tile(xs[0], x, t * PTILE, wave, lane);
  asm volatile("s_waitcnt vmcnt(0) lgkmcnt(0)" ::: "memory");
  __builtin_amdgcn_s_barrier();
  asm volatile("" ::: "memory");

  int cur = 0;
  for (; t < NTILES; t += VBLK) {
    const int pbase = t * PTILE;
    stage_tile(xs[cur ^ 1], x, (t + VBLK) * PTILE, wave, lane);
    int4 c4;
    {
      const int cb = pbase + pg * 4;
      if (cb + 3 < NPTS) {
        c4 = *(const int4*)(cluster + cb);
      } else {
        c4.x = cluster[cb + 0 < NPTS ? cb + 0 : NPTS - 1];
        c4.y = cluster[cb + 1 < NPTS ? cb + 1 : NPTS - 1];
        c4.z = cluster[cb + 2 < NPTS ? cb + 2 : NPTS - 1];
        c4.w = cluster[cb + 3 < NPTS ? cb + 3 : NPTS - 1];
      }
    }
    asm volatile("" ::: "memory");

    float4 acc[4];
#pragma unroll
    for (int pp = 0; pp < 4; ++pp) acc[pp] = bv4;
#pragma unroll 4
    for (int j4 = 0; j4 < 16; ++j4) {
      float4 wv[4];
#pragma unroll
      for (int e = 0; e < 4; ++e)
        wv[e] = *(const float4*)(Wt + (j4 * 4 + e) * DF + f0);
      const int xoff = (j4 ^ pg) * 4;
#pragma unroll
      for (int pp = 0; pp < 4; ++pp) {
        float4 xv = *(const float4*)(&xs[cur][(pg * 4 + pp) * DF + xoff]);
        acc[pp].x = fmaf(xv.x, wv[0].x, acc[pp].x);
        acc[pp].y = fmaf(xv.x, wv[0].y, acc[pp].y);
        acc[pp].z = fmaf(xv.x, wv[0].z, acc[pp].z);
        acc[pp].w = fmaf(xv.x, wv[0].w, acc[pp].w);
        acc[pp].x = fmaf(xv.y, wv[1].x, acc[pp].x);
        acc[pp].y = fmaf(xv.y, wv[1].y, acc[pp].y);
        acc[pp].z = fmaf(xv.y, wv[1].z, acc[pp].z);
        acc[pp].w = fmaf(xv.y, wv[1].w, acc[pp].w);
        acc[pp].x = fmaf(xv.z, wv[2].x, acc[pp].x);
        acc[pp].y = fmaf(xv.z, wv[2].y, acc[pp].y);
        acc[pp].z = fmaf(xv.z, wv[2].z, acc[pp].z);
        acc[pp].w = fmaf(xv.z, wv[2].w, acc[pp].w);
        acc[pp].x = fmaf(xv.w, wv[3].x, acc[pp].x);
        acc[pp].y = fmaf(xv.w, wv[3].y, acc[pp].y);
        acc[pp].z = fmaf(xv.w, wv[3].z, acc[pp].z);
        acc[pp].w = fmaf(xv.w, wv[3].w, acc[pp].w);
      }
    }

#pragma unroll
    for (int pp = 0; pp < 4; ++pp) {
      const int p = pbase + pg * 4 + pp;
      if (p < NPTS) {
        const int cc = (pp == 0) ? c4.x : (pp == 1) ? c4.y
                       : (pp == 2) ? c4.z : c4.w;
        const float attn = __expf(Mv[p] - o2f(mmax_u[cc])) / denom[cc];
        float4 h;
        h.x = attn * acc[pp].x;
        h.y = attn * acc[pp].y;
        h.z = attn * acc[pp].z;
        h.w = attn * acc[pp].w;
        s1.x += h.x; s1.y += h.y; s1.z += h.z; s1.w += h.w;
        s2.x += h.x * h.x; s2.y += h.y * h.y;
        s2.z += h.z * h.z; s2.w += h.w * h.w;
        *(float4*)(out + (size_t)p * DF + f0) = h;  // raw h; bn+relu later
      }
    }

    asm volatile("s_waitcnt vmcnt(0)" ::: "memory");
    __builtin_amdgcn_s_barrier();
    asm volatile("" ::: "memory");
    cur ^= 1;
  }

  // block-reduce BN partial sums; alias xs as scratch (tiles are done)
  __syncthreads();
  float* red = &xs[0][0];
  *(float4*)(red + pg * DF + f0) = s1;
  *(float4*)(red + 1024 + pg * DF + f0) = s2;
  __syncthreads();
  if (tid < DF) {
    float a = 0.f, b = 0.f;
#pragma unroll
    for (int g = 0; g < 16; ++g) {
      a += red[g * DF + tid];
      b += red[1024 + g * DF + tid];
    }
    atomicAdd(sums + tid, a);
    atomicAdd(sums + DF + tid, b);
  }
}

__global__ void finalize_kernel(const float* __restrict__ sums,
                                const float* __restrict__ gamma,
                                const float* __restrict__ beta,
                                float* __restrict__ scale,
                                float* __restrict__ shift) {
  int d = threadIdx.x;
  float mean = sums[d] * (1.0f / NPTS);
  float var = sums[DF + d] * (1.0f / NPTS) - mean * mean;
  float s = gamma[d] * rsqrtf(var + BN_EPS);
  scale[d] = s;
  shift[d] = fmaf(-mean, s, beta[d]);
}

// out = relu(out*scale + shift), pure streaming, in place.
#define BNBLK 2048
__global__ void bnrelu_kernel(float* __restrict__ out,
                              const float* __restrict__ scale,
                              const float* __restrict__ shift) {
  const int g = blockIdx.x * TPB + threadIdx.x;  // 524288 threads
  const int c = g & 15;                          // column float4-chunk
  const float4 sc = *(const float4*)(scale + c * 4);
  const float4 sh = *(const float4*)(shift + c * 4);
  const int rstride = (BNBLK * TPB) >> 4;        // 32768 rows per step
  for (int r = g >> 4; r < NPTS; r += rstride) {
    float4* p = (float4*)(out + (size_t)r * DF) + c;
    float4 h = *p;
    h.x = fmaxf(fmaf(h.x, sc.x, sh.x), 0.f);
    h.y = fmaxf(fmaf(h.y, sc.y, sh.y), 0.f);
    h.z = fmaxf(fmaf(h.z, sc.z, sh.z), 0.f);
    h.w = fmaxf(fmaf(h.w, sc.w, sh.w), 0.f);
    *p = h;
  }
}

extern "C" void kernel_launch(void* const* d_in, const int* in_sizes, int n_in,
                              void* d_out, int out_size, void* d_ws,
                              size_t ws_size, hipStream_t stream) {
  const float* x = (const float*)d_in[1];
  const int* cluster = (const int*)d_in[2];
  const float* Wv = (const float*)d_in[3];
  const float* bv = (const float*)d_in[4];
  const float* Wk = (const float*)d_in[5];
  const float* bk = (const float*)d_in[6];
  const float* Wq = (const float*)d_in[7];
  const float* bq = (const float*)d_in[8];
  const float* gamma = (const float*)d_in[9];
  const float* beta = (const float*)d_in[10];
  float* out = (float*)d_out;

  float* ws = (float*)d_ws;
  unsigned* q_u = (unsigned*)ws;
  unsigned* mmax_u = (unsigned*)(ws + 640000);
  float* denom = ws + 650000;
  float* sums = ws + 660000;
  float* scale = ws + 660128;
  float* shift = ws + 660192;
  float* Mv = ws + 660256;

  // zero q_u / mmax_u / denom / sums (0u == sortable "-inf" sentinel)
  hipMemsetAsync(d_ws, 0, 660256 * sizeof(float), stream);

  // 1) fused Q+K: q_u segment-max + k rows staged in d_out
  qk_kernel<<<QKBLK, TPB, 0, stream>>>(x, cluster, Wq, bq, Wk, bk, q_u, out);
  // 2) M = q[c].k, mmax segment-max
  mdot_kernel<<<NTILES, TPB, 0, stream>>>(out, cluster, q_u, Mv, mmax_u);
  // 3) softmax denominators
  denom_kernel<<<(NPTS + 255) / 256, 256, 0, stream>>>(Mv, cluster, mmax_u,
                                                       denom);
  // 4) V projection + attn weighting + BN stats, h -> out
  v_kernel<<<VBLK, TPB, 0, stream>>>(x, cluster, Wv, bv, mmax_u, denom, Mv,
                                     sums, out);
  // 5) BN scale/shift
  finalize_kernel<<<1, 64, 0, stream>>>(sums, gamma, beta, scale, shift);
  // 6) streaming bn+relu in place
  bnrelu_kernel<<<BNBLK, TPB, 0, stream>>>(out, scale, shift);
}